// Round 1
// baseline (204.595 us; speedup 1.0000x reference)
//
#include <hip/hip_runtime.h>
#include <math.h>

#define G      7
#define NB     2
#define NC     20
#define NCELL  (G*G)          // 49
#define NBOX   (NCELL*NB)     // 98
#define CH     (NB*5 + NC)    // 30
#define RAWF   (NCELL*CH)     // 1470
#define BATCH  8192
#define THR_CONF 0.5f
#define THR_NMS  0.3f

__device__ __forceinline__ float sigmoidf_(float x) {
    return 1.0f / (1.0f + expf(-x));
}

__global__ __launch_bounds__(128) void yolo_nms_kernel(
    const float* __restrict__ p,
    float* __restrict__ out_boxes,   // [B,98,4]
    float* __restrict__ out_scores,  // [B,98]
    float* __restrict__ out_labels,  // [B,98]
    float* __restrict__ out_keep)    // [B,98]
{
#pragma clang fp contract(off)
    __shared__ float raw[RAWF];
    __shared__ float bx1[NBOX], by1[NBOX], bx2[NBOX], by2[NBOX], sc[NBOX];
    __shared__ int   lab[NBOX];
    __shared__ unsigned char val[NBOX];
    __shared__ float sx1[NBOX], sy1[NBOX], sx2[NBOX], sy2[NBOX];
    __shared__ int   slab[NBOX], sorig[NBOX];
    __shared__ unsigned char sval[NBOX];
    __shared__ unsigned long long sup0[NBOX], sup1[NBOX];
    __shared__ unsigned long long keepm[2];

    const int b = blockIdx.x;
    const int t = threadIdx.x;

    // ---- stage input to LDS (coalesced float2) ----
    const float2* src = (const float2*)(p + (size_t)b * RAWF);
    float2* raw2 = (float2*)raw;
    for (int k = t; k < RAWF / 2; k += 128) raw2[k] = src[k];
    __syncthreads();

    // ---- decode ----
    if (t < NBOX) {
        const int cell = t >> 1, j = t & 1;
        const int r = cell / G, c = cell - r * G;
        const float* q = raw + cell * CH;
        float tx = q[j * 4 + 0], ty = q[j * 4 + 1];
        float tw = q[j * 4 + 2], th = q[j * 4 + 3];
        float gx = (sigmoidf_(tx) + (float)c) / 7.0f;
        float gy = (sigmoidf_(ty) + (float)r) / 7.0f;
        float hx = tw * 0.5f, hy = th * 0.5f;   // exact halving
        bx1[t] = gx - hx; by1[t] = gy - hy;
        bx2[t] = gx + hx; by2[t] = gy + hy;
        float s = sigmoidf_(q[8 + j]);
        sc[t] = s;
        val[t] = (s > THR_CONF) ? 1 : 0;
        // first-max argmax over 20 class logits (same per cell, redundant per box)
        float best = q[10]; int bi = 0;
        for (int k2 = 1; k2 < NC; ++k2) {
            float v2 = q[10 + k2];
            if (v2 > best) { best = v2; bi = k2; }
        }
        lab[t] = bi + 1;
    }
    __syncthreads();

    // ---- stable descending sort via rank counting (matches argsort(-scores)) ----
    if (t < NBOX) {
        const float st = sc[t];
        int rank = 0;
        for (int j = 0; j < NBOX; ++j) {
            float sj = sc[j];
            rank += (sj > st) || (sj == st && j < t);
        }
        sorig[rank] = t;
        sx1[rank] = bx1[t]; sy1[rank] = by1[t];
        sx2[rank] = bx2[t]; sy2[rank] = by2[t];
        slab[rank] = lab[t]; sval[rank] = val[t];
    }
    __syncthreads();

    // ---- suppression matrix column for sorted box t (98-bit mask in 2x u64) ----
    if (t < NBOX) {
        const float x1 = sx1[t], y1 = sy1[t], x2 = sx2[t], y2 = sy2[t];
        const int li = slab[t];
        const float areai = fmaxf(x2 - x1, 0.0f) * fmaxf(y2 - y1, 0.0f);
        unsigned long long m0 = 0ull, m1 = 0ull;
        for (int j = 0; j < NBOX; ++j) {
            float jx1 = sx1[j], jy1 = sy1[j], jx2 = sx2[j], jy2 = sy2[j];
            float ltx = fmaxf(x1, jx1), lty = fmaxf(y1, jy1);
            float rbx = fminf(x2, jx2), rby = fminf(y2, jy2);
            float w = fmaxf(rbx - ltx, 0.0f);
            float h = fmaxf(rby - lty, 0.0f);
            float inter = w * h;
            float areaj = fmaxf(jx2 - jx1, 0.0f) * fmaxf(jy2 - jy1, 0.0f);
            float uni = areai + areaj - inter;
            float iou = inter / fmaxf(uni, 1e-9f);
            bool s2 = (iou > THR_NMS) && (slab[j] == li);
            if (s2) {
                if (j < 64) m0 |= 1ull << j;
                else        m1 |= 1ull << (j - 64);
            }
        }
        sup0[t] = m0; sup1[t] = m1;
    }
    __syncthreads();

    // ---- serial greedy NMS scan (thread 0, bitmask) ----
    if (t == 0) {
        unsigned long long k0 = 0ull, k1 = 0ull;
        for (int i = 0; i < NBOX; ++i) {
            bool suppressed = ((k0 & sup0[i]) | (k1 & sup1[i])) != 0ull;
            bool k = sval[i] && !suppressed;
            if (k) {
                if (i < 64) k0 |= 1ull << i;
                else        k1 |= 1ull << (i - 64);
            }
        }
        keepm[0] = k0; keepm[1] = k1;
    }
    __syncthreads();

    // ---- outputs ----
    if (t < NBOX) {
        // boxes/scores/labels in original order
        float4 bb = make_float4(bx1[t], by1[t], bx2[t], by2[t]);
        ((float4*)(out_boxes + (size_t)b * (NBOX * 4)))[t] = bb;
        out_scores[(size_t)b * NBOX + t] = sc[t];
        out_labels[(size_t)b * NBOX + t] = (float)lab[t];
        // keep: sorted slot t scatters to original index sorig[t]
        unsigned long long km = (t < 64) ? keepm[0] : keepm[1];
        int bit = (t < 64) ? t : (t - 64);
        float kv = ((km >> bit) & 1ull) ? 1.0f : 0.0f;
        out_keep[(size_t)b * NBOX + sorig[t]] = kv;
    }
}

extern "C" void kernel_launch(void* const* d_in, const int* in_sizes, int n_in,
                              void* d_out, int out_size, void* d_ws, size_t ws_size,
                              hipStream_t stream) {
    const float* p = (const float*)d_in[0];
    float* out = (float*)d_out;
    // layout: boxes [B,98,4] | scores [B,98] | labels [B,98] | keep [B,98]
    float* out_boxes  = out;
    float* out_scores = out + (size_t)BATCH * NBOX * 4;
    float* out_labels = out_scores + (size_t)BATCH * NBOX;
    float* out_keep   = out_labels + (size_t)BATCH * NBOX;

    yolo_nms_kernel<<<BATCH, 128, 0, stream>>>(p, out_boxes, out_scores,
                                               out_labels, out_keep);
}

// Round 2
// 129.525 us; speedup vs baseline: 1.5796x; 1.5796x over previous
//
#include <hip/hip_runtime.h>
#include <math.h>

#define G      7
#define NB     2
#define NC     20
#define NCELL  (G*G)          // 49
#define NBOX   (NCELL*NB)     // 98
#define CH     (NB*5 + NC)    // 30
#define RAWF   (NCELL*CH)     // 1470
#define BATCH  8192

__device__ __forceinline__ float sigmoidf_(float x) {
    return 1.0f / (1.0f + expf(-x));
}

__global__ __launch_bounds__(128) void yolo_nms_kernel(
    const float* __restrict__ p,
    float* __restrict__ out_boxes,   // [B,98,4]
    float* __restrict__ out_scores,  // [B,98]
    float* __restrict__ out_labels,  // [B,98]
    float* __restrict__ out_keep)    // [B,98]
{
#pragma clang fp contract(off)
    // raw[] holds the staged input during decode; afterwards it is dead and
    // re-used (aliased) for the sorted-box arrays + suppression masks.
    __shared__ __align__(16) float raw[RAWF];           // 5880 B
    __shared__ float4 cbox[NBOX];                       // compacted valid boxes
    __shared__ float2 csl[NBOX];                        // (score, label)
    __shared__ int    corig[NBOX];                      // original index
    __shared__ float  keepf[NBOX];
    __shared__ int    wcnt[2];
    __shared__ unsigned long long keepm[2];

    // aliases into raw[] (all offsets 16B/8B aligned; total 4312 B <= 5880 B)
    float4*             sbox  = (float4*)raw;                          // 98*16
    float2*             smeta = (float2*)(raw + 392);                  // (area,label)
    unsigned long long* sup0  = (unsigned long long*)(raw + 588);
    unsigned long long* sup1  = (unsigned long long*)(raw + 784);
    int*                sorig = (int*)(raw + 980);

    const int b = blockIdx.x;
    const int t = threadIdx.x;

    // ---- stage input to LDS (coalesced float2) ----
    const float2* src = (const float2*)(p + (size_t)b * RAWF);
    float2* raw2 = (float2*)raw;
    for (int k = t; k < RAWF / 2; k += 128) raw2[k] = src[k];
    if (t < NBOX) keepf[t] = 0.0f;
    __syncthreads();

    // ---- decode; write NMS-independent outputs immediately ----
    float4 bb = make_float4(0.f, 0.f, 0.f, 0.f);
    float  s  = 0.0f;
    int    lb = 0;
    bool   valid = false;
    if (t < NBOX) {
        const int cell = t >> 1, j = t & 1;
        const int r = cell / G, c = cell - r * G;
        const float2* q2 = (const float2*)(raw + cell * CH);  // 8B aligned
        float2 xy = q2[2 * j];       // tx, ty
        float2 wh = q2[2 * j + 1];   // tw, th
        float gx = (sigmoidf_(xy.x) + (float)c) / 7.0f;
        float gy = (sigmoidf_(xy.y) + (float)r) / 7.0f;
        float hx = wh.x * 0.5f, hy = wh.y * 0.5f;
        bb = make_float4(gx - hx, gy - hy, gx + hx, gy + hy);
        s = sigmoidf_(raw[cell * CH + 8 + j]);
        valid = (s > 0.5f);
        // first-max argmax over 20 class logits (float2 reads)
        float2 c0 = q2[5];
        float best = c0.x; int bi = 0;
        if (c0.y > best) { best = c0.y; bi = 1; }
        for (int k2 = 1; k2 < 10; ++k2) {
            float2 cv = q2[5 + k2];
            if (cv.x > best) { best = cv.x; bi = 2 * k2; }
            if (cv.y > best) { best = cv.y; bi = 2 * k2 + 1; }
        }
        lb = bi + 1;
        ((float4*)(out_boxes + (size_t)b * (NBOX * 4)))[t] = bb;
        out_scores[(size_t)b * NBOX + t] = s;
        out_labels[(size_t)b * NBOX + t] = (float)lb;
    }

    // ---- order-preserving compaction of valid boxes (wave ballot) ----
    unsigned long long bm = __ballot(valid);
    const int lane = t & 63, wv = t >> 6;
    if (lane == 0) wcnt[wv] = __popcll(bm);
    const int pos = __popcll(bm & ((1ull << lane) - 1ull));
    __syncthreads();
    const int V = wcnt[0] + wcnt[1];   // valid boxes = prefix of sorted order
    if (valid) {
        int ci = (wv ? wcnt[0] : 0) + pos;
        cbox[ci]  = bb;
        csl[ci]   = make_float2(s, (float)lb);
        corig[ci] = t;
    }
    __syncthreads();

    // ---- stable descending rank-sort of the V valid boxes ----
    if (t < V) {
        const float st = csl[t].x;
        int rank = 0;
        for (int j = 0; j < V; ++j) {
            float sj = csl[j].x;
            rank += (sj > st) || ((sj == st) && (j < t));
        }
        float4 bt = cbox[t];
        float area = fmaxf(bt.z - bt.x, 0.0f) * fmaxf(bt.w - bt.y, 0.0f);
        sbox[rank]  = bt;
        smeta[rank] = make_float2(area, csl[t].y);
        sorig[rank] = corig[t];
    }
    __syncthreads();

    // ---- triangular suppression masks (j < t only; matches idx<i mask) ----
    if (t < V) {
        const float4 bi = sbox[t];
        const float2 mi = smeta[t];
        unsigned long long m0 = 0ull, m1 = 0ull;
        // exact, division-free NMS predicate:
        // RN(inter/uc) > 0.3f  <=>  inter > (0.3f + 2^-26) * uc  (exact in f64)
        const double UD = (double)0.3f + 0x1p-26;
        for (int j = 0; j < t; ++j) {
            float4 bj = sbox[j];
            float2 mj = smeta[j];
            float ltx = fmaxf(bi.x, bj.x), lty = fmaxf(bi.y, bj.y);
            float rbx = fminf(bi.z, bj.z), rby = fminf(bi.w, bj.w);
            float w = fmaxf(rbx - ltx, 0.0f);
            float h = fmaxf(rby - lty, 0.0f);
            float inter = w * h;
            float uni = mi.x + mj.x - inter;
            float uc = fmaxf(uni, 1e-9f);
            bool hit = ((double)inter > UD * (double)uc) && (mi.y == mj.y);
            unsigned long long hb = (unsigned long long)hit;
            if (j < 64) m0 |= hb << j;          // wave-uniform branch
            else        m1 |= hb << (j - 64);
        }
        sup0[t] = m0; sup1[t] = m1;
    }
    __syncthreads();

    // ---- serial greedy scan over the V sorted-valid boxes ----
    if (t == 0) {
        unsigned long long k0 = 0ull, k1 = 0ull;
        for (int i = 0; i < V; ++i) {
            bool suppressed = ((k0 & sup0[i]) | (k1 & sup1[i])) != 0ull;
            if (!suppressed) {
                if (i < 64) k0 |= 1ull << i;
                else        k1 |= 1ull << (i - 64);
            }
        }
        keepm[0] = k0; keepm[1] = k1;
    }
    __syncthreads();

    // ---- scatter keep bits to original order, write out ----
    if (t < V) {
        unsigned long long km = (t < 64) ? keepm[0] : keepm[1];
        keepf[sorig[t]] = ((km >> (t & 63)) & 1ull) ? 1.0f : 0.0f;
    }
    __syncthreads();
    if (t < NBOX) out_keep[(size_t)b * NBOX + t] = keepf[t];
}

extern "C" void kernel_launch(void* const* d_in, const int* in_sizes, int n_in,
                              void* d_out, int out_size, void* d_ws, size_t ws_size,
                              hipStream_t stream) {
    const float* p = (const float*)d_in[0];
    float* out = (float*)d_out;
    float* out_boxes  = out;
    float* out_scores = out + (size_t)BATCH * NBOX * 4;
    float* out_labels = out_scores + (size_t)BATCH * NBOX;
    float* out_keep   = out_labels + (size_t)BATCH * NBOX;

    yolo_nms_kernel<<<BATCH, 128, 0, stream>>>(p, out_boxes, out_scores,
                                               out_labels, out_keep);
}